// Round 13
// baseline (323.670 us; speedup 1.0000x reference)
//
#include <hip/hip_runtime.h>
#include <hip/hip_bf16.h>

typedef unsigned short u16;
typedef __attribute__((ext_vector_type(8))) short bf16x8;
typedef __attribute__((ext_vector_type(4))) float f32x4;

constexpr int B_ = 16, C_ = 192, H_ = 56, W_ = 56;
constexpr int N_ = H_ * W_;   // 3136
constexpr int NP = 3200;      // padded n-stride for attnt/zinv/ssq only
constexpr int A_ = 768;       // attn_dim
constexpr int Dq = 192;       // d_qk
constexpr int Vd = 384;       // d_v
constexpr float EPSf = 1e-6f;

union U8 { bf16x8 v; u16 s[8]; unsigned u[4]; };

__device__ __forceinline__ float bits2f(u16 u) {
  return __uint_as_float(((unsigned)u) << 16);
}
__device__ __forceinline__ u16 f2bits(float f) {
  __hip_bfloat16 h = __float2bfloat16(f);
  u16 u;
  __builtin_memcpy(&u, &h, sizeof(u));
  return u;
}
__device__ __forceinline__ float silu_f(float v) { return v / (1.0f + __expf(-v)); }
__device__ __forceinline__ float sigm_f(float v) { return 1.0f / (1.0f + __expf(-v)); }

__device__ __forceinline__ f32x4 MFMA(bf16x8 a, bf16x8 b, f32x4 c) {
  return __builtin_amdgcn_mfma_f32_16x16x32_bf16(a, b, c, 0, 0, 0);
}
__device__ __forceinline__ int swz(int row) { return (row & 7) ^ ((row >> 3) & 7); }

// ============ K0: weight pre-convert f32 -> bf16 (pw, gw, ow); block 252 zeros kfp
__global__ __launch_bounds__(256) void k_prep(const float* __restrict__ pw,
                                              const float* __restrict__ gw,
                                              const float* __restrict__ ow,
                                              u16* __restrict__ pwb,
                                              u16* __restrict__ gwb,
                                              u16* __restrict__ owb,
                                              float* __restrict__ kfp) {
  const int bid = blockIdx.x;
  if (bid == 252) {
    for (int i = threadIdx.x; i < B_ * Dq; i += 256) kfp[i] = 0.f;
    return;
  }
  const size_t base = ((size_t)bid * 256 + threadIdx.x) * 8;
  const float* src;
  u16* dst;
  size_t off;
  if (bid < 72) { src = pw; dst = pwb; off = base; }
  else if (bid < 216) { src = gw; dst = gwb; off = base - 147456; }
  else { src = ow; dst = owb; off = base - 442368; }
  float4 v0 = *(const float4*)&src[off];
  float4 v1 = *(const float4*)&src[off + 4];
  U8 r;
  r.s[0] = f2bits(v0.x); r.s[1] = f2bits(v0.y); r.s[2] = f2bits(v0.z); r.s[3] = f2bits(v0.w);
  r.s[4] = f2bits(v1.x); r.s[5] = f2bits(v1.y); r.s[6] = f2bits(v1.z); r.s[7] = f2bits(v1.w);
  *(bf16x8*)&dst[off] = r.v;
}

// ============ K1: proj GEMM  y0t[b][n][o] = sum_c pw[o,c]*x[b,c,n] + pb[o]
__global__ __launch_bounds__(256) void k_proj(const float* __restrict__ x,
                                              const u16* __restrict__ pwb,
                                              const float* __restrict__ pb,
                                              u16* __restrict__ y0t) {
  const int n0 = blockIdx.x * 64;
  const int oy = blockIdx.y;  // 0..2
  const int b = blockIdx.z;
  __shared__ u16 Xt[64][200];  // [n][c], 400B stride
  __shared__ u16 Wa[256][32];  // [o][k32], swizzled 16B blocks
  const int t = threadIdx.x;
  const int lane = t & 63, wid = t >> 6;
  const int fr = lane & 15, fg = lane >> 4;

  // stage Xt: x[b][c][n] -> Xt[n][c]
  {
    const int p = t & 31, co = t >> 5;
    const float* xb = x + (size_t)b * C_ * N_ + n0 + 2 * p;
#pragma unroll
    for (int rnd = 0; rnd < 3; ++rnd) {
      const int c0 = rnd * 64 + co * 8;
      float2 v[8];
#pragma unroll
      for (int i = 0; i < 8; ++i) v[i] = *(const float2*)&xb[(size_t)(c0 + i) * N_];
      U8 r0, r1;
#pragma unroll
      for (int i = 0; i < 8; ++i) { r0.s[i] = f2bits(v[i].x); r1.s[i] = f2bits(v[i].y); }
      *(bf16x8*)&Xt[2 * p][c0] = r0.v;
      *(bf16x8*)&Xt[2 * p + 1][c0] = r1.v;
    }
  }

  f32x4 acc[4][4];
#pragma unroll
  for (int mi = 0; mi < 4; ++mi)
#pragma unroll
    for (int ni = 0; ni < 4; ++ni) acc[mi][ni] = (f32x4){0.f, 0.f, 0.f, 0.f};

  const int orow_c = t >> 2, oct_c = t & 3;
  U8 wreg[4];
#pragma unroll
  for (int jj = 0; jj < 4; ++jj)
    wreg[jj].v = *(const bf16x8*)&pwb[(size_t)(oy * 256 + orow_c + 64 * jj) * C_ + oct_c * 8];

  for (int ks = 0; ks < 6; ++ks) {
    __syncthreads();
#pragma unroll
    for (int jj = 0; jj < 4; ++jj) {
      const int orow = orow_c + 64 * jj;
      const int sw = (orow >> 1) & 3;
      *(bf16x8*)&Wa[orow][(oct_c ^ sw) * 8] = wreg[jj].v;
    }
    __syncthreads();
    if (ks < 5) {
#pragma unroll
      for (int jj = 0; jj < 4; ++jj)
        wreg[jj].v = *(const bf16x8*)&pwb[(size_t)(oy * 256 + orow_c + 64 * jj) * C_ +
                                          (ks + 1) * 32 + oct_c * 8];
    }
    bf16x8 bfrag[4];
#pragma unroll
    for (int ni = 0; ni < 4; ++ni)
      bfrag[ni] = *(const bf16x8*)&Xt[ni * 16 + fr][ks * 32 + fg * 8];
    __builtin_amdgcn_s_setprio(1);
#pragma unroll
    for (int mi = 0; mi < 4; ++mi) {
      const int ar = wid * 64 + mi * 16 + fr;
      bf16x8 a = *(const bf16x8*)&Wa[ar][(fg ^ ((ar >> 1) & 3)) * 8];
#pragma unroll
      for (int ni = 0; ni < 4; ++ni) acc[mi][ni] = MFMA(a, bfrag[ni], acc[mi][ni]);
    }
    __builtin_amdgcn_s_setprio(0);
  }
#pragma unroll
  for (int mi = 0; mi < 4; ++mi) {
    const int o4 = oy * 256 + wid * 64 + mi * 16 + fg * 4;
    const float b0 = pb[o4], b1 = pb[o4 + 1], b2 = pb[o4 + 2], b3 = pb[o4 + 3];
#pragma unroll
    for (int ni = 0; ni < 4; ++ni) {
      const int n = n0 + ni * 16 + fr;
      ushort4 pk;
      pk.x = f2bits(acc[mi][ni][0] + b0);
      pk.y = f2bits(acc[mi][ni][1] + b1);
      pk.z = f2bits(acc[mi][ni][2] + b2);
      pk.w = f2bits(acc[mi][ni][3] + b3);
      *(ushort4*)&y0t[((size_t)b * N_ + n) * A_ + o4] = pk;
    }
  }
}

// ============ K2: depthwise 3x3 + bias + residual, sliding-window; fused kfmean atomics
__global__ __launch_bounds__(256) void k_dwc(const u16* __restrict__ y0t,
                                             const float* __restrict__ cw,
                                             const float* __restrict__ cb,
                                             u16* __restrict__ yt,
                                             float* __restrict__ kfp) {
  const int pid = blockIdx.x;
  const int L = (pid & 7) * 336 + (pid >> 3);  // 2688 = 8*336
  const int h = L % 56, at = (L / 56) % 3, b = L / 168;
  const int t = threadIdx.x;
  const int a = at * 256 + (t & 31) * 8;
  const int ws0 = (t >> 5) * 7;  // 7-wide consecutive w strip
  float w9[9][8];
  float bias[8];
#pragma unroll
  for (int j = 0; j < 8; ++j) {
    bias[j] = cb[a + j];
#pragma unroll
    for (int k = 0; k < 9; ++k) w9[k][j] = cw[(a + j) * 9 + k];
  }
  const u16* src = y0t + (size_t)b * N_ * A_ + a;
  u16* dst = yt + (size_t)b * N_ * A_ + a;
  const bool hok0 = h > 0, hok2 = h < 55;

  U8 cm[3], cc[3], cp[3];  // cols w-1, w, w+1; rows h-1,h,h+1
  auto zero8 = [](U8& x) { x.u[0] = x.u[1] = x.u[2] = x.u[3] = 0u; };
  auto loadcol = [&](U8 col[3], int w) {
    if ((unsigned)w < 56u) {
      if (hok0) col[0].v = *(const bf16x8*)&src[(size_t)((h - 1) * 56 + w) * A_];
      else zero8(col[0]);
      col[1].v = *(const bf16x8*)&src[(size_t)(h * 56 + w) * A_];
      if (hok2) col[2].v = *(const bf16x8*)&src[(size_t)((h + 1) * 56 + w) * A_];
      else zero8(col[2]);
    } else {
      zero8(col[0]); zero8(col[1]); zero8(col[2]);
    }
  };
  loadcol(cm, ws0 - 1);
  loadcol(cc, ws0);

  float kacc[8] = {0.f, 0.f, 0.f, 0.f, 0.f, 0.f, 0.f, 0.f};
#pragma unroll
  for (int i = 0; i < 7; ++i) {
    const int w = ws0 + i;
    loadcol(cp, w + 1);
    U8 o;
#pragma unroll
    for (int j = 0; j < 8; ++j) {
      float s = bias[j] + bits2f(cc[1].s[j]);  // bias + residual(center)
      s = fmaf(w9[0][j], bits2f(cm[0].s[j]), s);
      s = fmaf(w9[1][j], bits2f(cc[0].s[j]), s);
      s = fmaf(w9[2][j], bits2f(cp[0].s[j]), s);
      s = fmaf(w9[3][j], bits2f(cm[1].s[j]), s);
      s = fmaf(w9[4][j], bits2f(cc[1].s[j]), s);
      s = fmaf(w9[5][j], bits2f(cp[1].s[j]), s);
      s = fmaf(w9[6][j], bits2f(cm[2].s[j]), s);
      s = fmaf(w9[7][j], bits2f(cc[2].s[j]), s);
      s = fmaf(w9[8][j], bits2f(cp[2].s[j]), s);
      o.s[j] = f2bits(s);
      const int ch = a + j;
      if (ch >= 192 && ch < 384) kacc[j] += silu_f(s);
    }
    *(bf16x8*)&dst[(size_t)(h * 56 + w) * A_] = o.v;
#pragma unroll
    for (int r = 0; r < 3; ++r) { cm[r] = cc[r]; cc[r] = cp[r]; }
  }

  // block-reduce kacc over the 8 w-strips, one atomicAdd per channel in [192,384)
  __shared__ float red[8][256];
  if (at < 2) {
    const int cbase = (t & 31) * 8, wl = t >> 5;
#pragma unroll
    for (int j = 0; j < 8; ++j) red[wl][cbase + j] = kacc[j];
    __syncthreads();
    float s = 0.f;
#pragma unroll
    for (int i = 0; i < 8; ++i) s += red[i][t];
    const int ac = at * 256 + t;
    if (ac >= 192 && ac < 384) atomicAdd(&kfp[b * Dq + (ac - 192)], s);
  }
}

// ============ K4: zinv (NP stride, pad zeroed) + ssq zeroing
__global__ __launch_bounds__(256) void k_z(const u16* __restrict__ yt,
                                           const float* __restrict__ kfp,
                                           float* __restrict__ zinv,
                                           float* __restrict__ ssq) {
  const int b = blockIdx.y;
  const int n = blockIdx.x * 256 + threadIdx.x;
  __shared__ float kf[192];
  if (threadIdx.x < 192)
    kf[threadIdx.x] = kfp[b * Dq + threadIdx.x] * (1.0f / (float)N_);
  __syncthreads();
  if (n < NP) {
    if (n < N_) {
      const u16* p = yt + ((size_t)b * N_ + n) * A_;
      float z = 0;
#pragma unroll
      for (int j = 0; j < 24; ++j) {
        U8 u;
        u.v = *(const bf16x8*)&p[j * 8];
#pragma unroll
        for (int i = 0; i < 8; ++i) z = fmaf(kf[j * 8 + i], silu_f(bits2f(u.s[i])), z);
      }
      zinv[(size_t)b * NP + n] = 1.0f / (z + EPSf);
    } else {
      zinv[(size_t)b * NP + n] = 0.f;
    }
    ssq[(size_t)b * NP + n] = 0.f;
  }
}

// ============ K5: vk GEMM, split-K over N (7 chunks), 128v x 192d tiles.
__global__ __launch_bounds__(256) void k_vk(const u16* __restrict__ yt,
                                            float* __restrict__ vkpart) {
  const int pid = blockIdx.x;  // 336 = 8*42
  const int L = (pid & 7) * 42 + (pid >> 3);
  const int ns = L % 7;
  const int vblk = (L / 7) % 3;
  const int b = L / 21;
  const int t = threadIdx.x;
  const int lane = t & 63, wid = t >> 6;
  const int fr = lane & 15, fg = lane >> 4;
  const int vbase = (wid >> 1) * 64, dbase = (wid & 1) * 96;

  __shared__ u16 T[320 * 64];  // rows 0..191: K(d, silu); rows 192..319: V
  unsigned* T32 = (unsigned*)T;

  const int oct0 = t & 7;
  const int pair = (t >> 3) & 31;
  const int nb0 = ns * 448;

  U8 pre[5][2];
  auto load_pre = [&](int n0) {
    const int n = nb0 + n0 + pair * 2;
#pragma unroll
    for (int j = 0; j < 5; ++j) {
      const int oct = oct0 + 8 * j;
      const u16* srcp;
      if (j < 3)
        srcp = yt + ((size_t)b * N_ + n) * A_ + 192 + oct * 8;
      else
        srcp = yt + ((size_t)b * N_ + n) * A_ + 384 + vblk * 128 + (oct - 24) * 8;
      pre[j][0].v = *(const bf16x8*)srcp;
      pre[j][1].v = *(const bf16x8*)(srcp + A_);
      if (j < 3) {
#pragma unroll
        for (int i = 0; i < 8; ++i) {
          pre[j][0].s[i] = f2bits(silu_f(bits2f(pre[j][0].s[i])));
          pre[j][1].s[i] = f2bits(silu_f(bits2f(pre[j][1].s[i])));
        }
      }
    }
  };

  f32x4 acc[4][6];
#pragma unroll
  for (int mi = 0; mi < 4; ++mi)
#pragma unroll
    for (int ni = 0; ni < 6; ++ni) acc[mi][ni] = (f32x4){0.f, 0.f, 0.f, 0.f};

  load_pre(0);
  for (int s = 0; s < 7; ++s) {
    __syncthreads();
#pragma unroll
    for (int j = 0; j < 5; ++j) {
      const int rowb = (oct0 + 8 * j) * 8;
#pragma unroll
      for (int i = 0; i < 8; ++i) {
        const int row = rowb + i;
        const int sw = swz(row);
        const unsigned val =
            ((unsigned)pre[j][0].s[i] & 0xffffu) | (((unsigned)pre[j][1].s[i]) << 16);
        T32[row * 32 + (pair ^ (sw << 2))] = val;
      }
    }
    __syncthreads();
    if (s < 6) load_pre((s + 1) * 64);
    __builtin_amdgcn_s_setprio(1);
#pragma unroll
    for (int kf2 = 0; kf2 < 2; ++kf2) {
      bf16x8 bfrag[6];
#pragma unroll
      for (int ni = 0; ni < 6; ++ni) {
        const int row = dbase + ni * 16 + fr;
        bfrag[ni] = *(const bf16x8*)&T[row * 64 + ((kf2 * 32 + fg * 8) ^ (swz(row) << 3))];
      }
#pragma unroll
      for (int mi = 0; mi < 4; ++mi) {
        const int row = 192 + vbase + mi * 16 + fr;
        bf16x8 a = *(const bf16x8*)&T[row * 64 + ((kf2 * 32 + fg * 8) ^ (swz(row) << 3))];
#pragma unroll
        for (int ni = 0; ni < 6; ++ni) acc[mi][ni] = MFMA(a, bfrag[ni], acc[mi][ni]);
      }
    }
    __builtin_amdgcn_s_setprio(0);
  }
  float* base = vkpart + (((size_t)ns * 16 + b) * 3 + vblk) * (128 * 192);
#pragma unroll
  for (int mi = 0; mi < 4; ++mi)
#pragma unroll
    for (int ni = 0; ni < 6; ++ni) {
      const int v = vbase + mi * 16 + fg * 4;
      const int d = dbase + ni * 16 + fr;
      float* o = base + (size_t)v * 192 + d;
      o[0] = acc[mi][ni][0];
      o[192] = acc[mi][ni][1];
      o[384] = acc[mi][ni][2];
      o[576] = acc[mi][ni][3];
    }
}

// ============ K5b: reduce 7 partials -> vkb bf16 [b][384][192] (with 1/N)
__global__ __launch_bounds__(256) void k_vkred(const float* __restrict__ vkpart,
                                               u16* __restrict__ vkb) {
  const size_t e = ((size_t)blockIdx.x * 256 + threadIdx.x) * 8;
  constexpr size_t NSSTRIDE = (size_t)16 * 3 * 128 * 192;
  float4 s0 = {0, 0, 0, 0}, s1 = {0, 0, 0, 0};
#pragma unroll
  for (int ns = 0; ns < 7; ++ns) {
    float4 a0 = *(const float4*)&vkpart[ns * NSSTRIDE + e];
    float4 a1 = *(const float4*)&vkpart[ns * NSSTRIDE + e + 4];
    s0.x += a0.x; s0.y += a0.y; s0.z += a0.z; s0.w += a0.w;
    s1.x += a1.x; s1.y += a1.y; s1.z += a1.z; s1.w += a1.w;
  }
  const float sc = 1.0f / (float)N_;
  U8 r;
  r.s[0] = f2bits(s0.x * sc); r.s[1] = f2bits(s0.y * sc);
  r.s[2] = f2bits(s0.z * sc); r.s[3] = f2bits(s0.w * sc);
  r.s[4] = f2bits(s1.x * sc); r.s[5] = f2bits(s1.y * sc);
  r.s[6] = f2bits(s1.z * sc); r.s[7] = f2bits(s1.w * sc);
  *(bf16x8*)&vkb[e] = r.v;
}

// ============ K6: fused attn0 + gate. 192v x 128n block, wave tile 96v x 64n.
// Double-buffered 40KB LDS, one barrier/iter, NO VGPR cap, ssq epilogue.
__global__ __launch_bounds__(256) void k_gateattn(const u16* __restrict__ yt,
                                                  const float* __restrict__ zinv,
                                                  const u16* __restrict__ vkb,
                                                  const u16* __restrict__ gwb,
                                                  const float* __restrict__ gb,
                                                  u16* __restrict__ attnt,
                                                  float* __restrict__ ssq) {
  const int pid = blockIdx.x;
  const int L = (pid & 7) * 100 + (pid >> 3);  // 800 = 8*100
  const int vh = L & 1;
  const int n0 = ((L >> 1) % 25) * 128;
  const int b = L / 50;
  const int t = threadIdx.x;
  const int lane = t & 63, wid = t >> 6, wm = wid >> 1, wn = wid & 1;
  const int fr = lane & 15, fg = lane >> 4;
  __shared__ u16 T[2][320 * 64];  // rows 0..191: W; rows 192..319: X (swizzled octets)
  const u16* yb = yt + (size_t)b * N_ * A_;
  const u16* wb0 = vkb + ((size_t)b * Vd + vh * 192) * 192;  // attn0 W, stride 192
  const u16* wb1 = gwb + (size_t)(vh * 192) * A_;            // gate W, stride 768

  const int oct = t & 7, rowb = t >> 3;  // 8 octets, 32 row-groups
  U8 pre[10];
  auto loadPre = [&](int nit) {
    if (nit < 3) {
      const int ks = nit * 64;
#pragma unroll
      for (int j = 0; j < 6; ++j)
        pre[j].v = *(const bf16x8*)&wb0[(size_t)(rowb + 32 * j) * 192 + ks + oct * 8];
#pragma unroll
      for (int j = 6; j < 10; ++j) {
        const int n = min(n0 + rowb + 32 * (j - 6), N_ - 1);
        pre[j].v = *(const bf16x8*)&yb[(size_t)n * A_ + ks + oct * 8];
      }
    } else {
      const int ks = (nit - 3) * 64;
#pragma unroll
      for (int j = 0; j < 6; ++j)
        pre[j].v = *(const bf16x8*)&wb1[(size_t)(rowb + 32 * j) * A_ + ks + oct * 8];
#pragma unroll
      for (int j = 6; j < 10; ++j) {
        const int n = min(n0 + rowb + 32 * (j - 6), N_ - 1);
        pre[j].v = *(const bf16x8*)&yb[(size_t)n * A_ + ks + oct * 8];
      }
    }
  };
  auto writeStage = [&](int nit, int buf) {
    const bool sl = (nit < 3);
    u16* Tb = &T[buf][0];
#pragma unroll
    for (int j = 0; j < 10; ++j) {
      const int r = rowb + 32 * j;
      U8 w = pre[j];
      if (sl && j >= 6) {
#pragma unroll
        for (int i = 0; i < 8; ++i) w.s[i] = f2bits(silu_f(bits2f(w.s[i])));
      }
      *(bf16x8*)&Tb[r * 64 + ((oct * 8) ^ (swz(r) << 3))] = w.v;
    }
  };

  f32x4 acc[6][4];
#pragma unroll
  for (int mi = 0; mi < 6; ++mi)
#pragma unroll
    for (int ni = 0; ni < 4; ++ni) acc[mi][ni] = (f32x4){0.f, 0.f, 0.f, 0.f};
  uint2 pp[6][4];

  loadPre(0);
  writeStage(0, 0);
  loadPre(1);
  __syncthreads();

  for (int it = 0; it < 15; ++it) {
    const int cur = it & 1;
    if (it < 14) writeStage(it + 1, cur ^ 1);
    if (it < 13) loadPre(it + 2);
    const u16* Tb = &T[cur][0];
    __builtin_amdgcn_s_setprio(1);
#pragma unroll
    for (int kf2 = 0; kf2 < 2; ++kf2) {
      bf16x8 bfr[4];
#pragma unroll
      for (int ni = 0; ni < 4; ++ni) {
        const int row = 192 + wn * 64 + ni * 16 + fr;
        bfr[ni] = *(const bf16x8*)&Tb[row * 64 + ((kf2 * 32 + fg * 8) ^ (swz(row) << 3))];
      }
#pragma unroll
      for (int mi = 0; mi < 6; ++mi) {
        const int row = wm * 96 + mi * 16 + fr;
        bf16x8 a = *(const bf16x8*)&Tb[row * 64 + ((kf2 * 32 + fg * 8) ^ (swz(row) << 3))];
#pragma unroll
        for (int ni = 0; ni < 4; ++ni) acc[mi][ni] = MFMA(a, bfr[ni], acc[mi][ni]);
      }
    }
    __builtin_amdgcn_s_setprio(0);
    if (it == 2) {  // attn0 done: apply 1/z, stash packed bf16, reset acc
      float zv[4];
#pragma unroll
      for (int ni = 0; ni < 4; ++ni)
        zv[ni] = zinv[(size_t)b * NP + n0 + wn * 64 + ni * 16 + fr];
#pragma unroll
      for (int mi = 0; mi < 6; ++mi)
#pragma unroll
        for (int ni = 0; ni < 4; ++ni) {
          const float z = zv[ni];
          unsigned a0 = ((unsigned)f2bits(acc[mi][ni][0] * z) & 0xffffu) |
                        (((unsigned)f2bits(acc[mi][ni][1] * z) & 0xffffu) << 16);
          unsigned a1 = ((unsigned)f2bits(acc[mi][ni][2] * z) & 0xffffu) |
                        (((unsigned)f2bits(acc[mi][ni][3] * z) & 0xffffu) << 16);
          pp[mi][ni] = make_uint2(a0, a1);
          acc[mi][ni] = (f32x4){0.f, 0.f, 0.f, 0.f};
        }
    }
    __syncthreads();
  }

  // ---- combine, write attnt[n][v] (NP stride), accumulate ssq
  float ssqa[4] = {0.f, 0.f, 0.f, 0.f};
#pragma unroll
  for (int mi = 0; mi < 6; ++mi) {
    const int vb = vh * 192 + wm * 96 + mi * 16 + fg * 4;
    const float g0 = gb[vb], g1 = gb[vb + 1], g2 = gb[vb + 2], g3 = gb[vb + 3];
#pragma unroll
    for (int ni = 0; ni < 4; ++ni) {
      const int n = n0 + wn * 64 + ni * 16 + fr;
      const uint2 p = pp[mi][ni];
      const float pv0 = bits2f((u16)(p.x & 0xffffu)), pv1 = bits2f((u16)(p.x >> 16));
      const float pv2 = bits2f((u16)(p.y & 0xffffu)), pv3 = bits2f((u16)(p.y >> 16));
      const float q0 = pv0 * sigm_f(acc[mi][ni][0] + g0);
      const float q1 = pv1 * sigm_f(acc[mi][ni][1] + g1);
      const float q2 = pv2 * sigm_f(acc[mi][ni][2] + g2);
      const float q3 = pv3 * sigm_f(acc[mi][ni][3] + g3);
      ushort4 o;
      o.x = f2bits(q0);
      o.y = f2bits(q1);
      o.z = f2bits(q2);
      o.w = f2bits(q3);
      *(ushort4*)&attnt[((size_t)b * NP + n) * Vd + vb] = o;
      ssqa[ni] += q0 * q0 + q1 * q1 + q2 * q2 + q3 * q3;
    }
  }
#pragma unroll
  for (int ni = 0; ni < 4; ++ni) {
    float ss = ssqa[ni];
    ss += __shfl_xor(ss, 16);
    ss += __shfl_xor(ss, 32);
    if (fg == 0) {
      const int n = n0 + wn * 64 + ni * 16 + fr;
      atomicAdd(&ssq[(size_t)b * NP + n], ss);
    }
  }
}

// ============ K7: final combine + out GEMM; rinv from precomputed ssq.
__global__ __launch_bounds__(256) void k_out(const u16* __restrict__ attnt,
                                             const u16* __restrict__ yt,
                                             const u16* __restrict__ owb,
                                             const float* __restrict__ ob,
                                             const float* __restrict__ anw,
                                             const float* __restrict__ svw,
                                             const float* __restrict__ ssq,
                                             float* __restrict__ out) {
  const int n0 = blockIdx.x * 64;
  const int b = blockIdx.y;
  __shared__ u16 T[256 * 64];  // rows 0..191: W(ow); rows 192..255: X (transformed)
  __shared__ float anws[384], svws[384];
  __shared__ float rinv[64];
  const int t = threadIdx.x;
  const int lane = t & 63, wid = t >> 6, wm = wid >> 1, wn = wid & 1;
  const int fr = lane & 15, fg = lane >> 4;
  for (int i = t; i < 384; i += 256) {
    anws[i] = anw[i];
    svws[i] = svw[i];
  }
  if (t < 64)
    rinv[t] = rsqrtf(ssq[(size_t)b * NP + n0 + t] * (1.0f / (float)Vd) + EPSf);

  const int oct = t & 7, rowb = t >> 3;
  U8 preW[6], preA[2], preV[2];
  auto loadPre = [&](int it) {
    const int ks = it * 64;
#pragma unroll
    for (int j = 0; j < 6; ++j)
      preW[j].v = *(const bf16x8*)&owb[(size_t)(rowb + 32 * j) * Vd + ks + oct * 8];
#pragma unroll
    for (int j = 0; j < 2; ++j) {
      const int n = rowb + 32 * j;
      preA[j].v = *(const bf16x8*)&attnt[((size_t)b * NP + n0 + n) * Vd + ks + oct * 8];
      preV[j].v = *(const bf16x8*)&yt[((size_t)b * N_ + n0 + n) * A_ + 384 + ks + oct * 8];
    }
  };

  f32x4 acc[6][2];
#pragma unroll
  for (int mi = 0; mi < 6; ++mi)
#pragma unroll
    for (int ni = 0; ni < 2; ++ni) acc[mi][ni] = (f32x4){0.f, 0.f, 0.f, 0.f};

  loadPre(0);
  __syncthreads();  // rinv/anws ready
  for (int it = 0; it < 6; ++it) {
#pragma unroll
    for (int j = 0; j < 6; ++j) {
      const int r = rowb + 32 * j;
      *(bf16x8*)&T[r * 64 + ((oct * 8) ^ (swz(r) << 3))] = preW[j].v;
    }
#pragma unroll
    for (int j = 0; j < 2; ++j) {
      const int n = rowb + 32 * j;
      const int r = 192 + n;
      const float ri = rinv[n];
      const int col0 = it * 64 + oct * 8;
      U8 o;
#pragma unroll
      for (int k = 0; k < 8; ++k)
        o.s[k] = f2bits(bits2f(preA[j].s[k]) * ri * anws[col0 + k] +
                        bits2f(preV[j].s[k]) * svws[col0 + k]);
      *(bf16x8*)&T[r * 64 + ((oct * 8) ^ (swz(r) << 3))] = o.v;
    }
    __syncthreads();
    if (it < 5) loadPre(it + 1);
    __builtin_amdgcn_s_setprio(1);
#pragma unroll
    for (int kf2 = 0; kf2 < 2; ++kf2) {
      bf16x8 bfr[2];
#pragma unroll
      for (int ni = 0; ni < 2; ++ni) {
        const int row = 192 + wn * 32 + ni * 16 + fr;
        bfr[ni] = *(const bf16x8*)&T[row * 64 + ((kf2 * 32 + fg * 8) ^ (swz(row) << 3))];
      }
#pragma unroll
      for (int mi = 0; mi < 6; ++mi) {
        const int row = wm * 96 + mi * 16 + fr;
        bf16x8 a = *(const bf16x8*)&T[row * 64 + ((kf2 * 32 + fg * 8) ^ (swz(row) << 3))];
        acc[mi][0] = MFMA(a, bfr[0], acc[mi][0]);
        acc[mi][1] = MFMA(a, bfr[1], acc[mi][1]);
      }
    }
    __builtin_amdgcn_s_setprio(0);
    if (it < 5) __syncthreads();
  }
#pragma unroll
  for (int mi = 0; mi < 6; ++mi) {
    const int c = wm * 96 + mi * 16 + fg * 4;
    const float b0 = ob[c], b1 = ob[c + 1], b2 = ob[c + 2], b3 = ob[c + 3];
#pragma unroll
    for (int ni = 0; ni < 2; ++ni) {
      const int n = n0 + wn * 32 + ni * 16 + fr;
      float* o = out + ((size_t)b * C_ + c) * N_ + n;
      o[0 * N_] = acc[mi][ni][0] + b0;
      o[1 * N_] = acc[mi][ni][1] + b1;
      o[2 * N_] = acc[mi][ni][2] + b2;
      o[3 * N_] = acc[mi][ni][3] + b3;
    }
  }
}

extern "C" void kernel_launch(void* const* d_in, const int* in_sizes, int n_in,
                              void* d_out, int out_size, void* d_ws, size_t ws_size,
                              hipStream_t stream) {
  (void)in_sizes; (void)n_in; (void)out_size; (void)ws_size;
  const float* x = (const float*)d_in[0];
  const float* pw = (const float*)d_in[1];
  const float* pb = (const float*)d_in[2];
  const float* cw = (const float*)d_in[3];
  const float* cb = (const float*)d_in[4];
  const float* gw = (const float*)d_in[5];
  const float* gb = (const float*)d_in[6];
  const float* anw = (const float*)d_in[7];
  const float* svw = (const float*)d_in[8];
  const float* ow = (const float*)d_in[9];
  const float* ob = (const float*)d_in[10];
  float* out = (float*)d_out;

  char* ws = (char*)d_ws;
  const size_t szY = (size_t)B_ * N_ * A_ * 2;  // 77,070,336
  u16* y0t = (u16*)(ws);                            // [B][N][A] bf16 (dead after dwc)
  u16* attnt = (u16*)(ws);                          // [B][NP][384] bf16 (39,321,600)
  float* vkpart = (float*)(ws + 39321600);          // [7][16][3][128][192] f32 (33,030,144)
  u16* vkb = (u16*)(ws + 72351744);                 // [16][384][192] bf16 (2,359,296) -> 74,711,040
  u16* yt = (u16*)(ws + szY);                       // [B][N][A] bf16
  char* ws2 = ws + 2 * szY;
  float* kfp = (float*)(ws2);                       // [16][192] f32 (12,288)
  float* zinv = (float*)(ws2 + 86016);              // [B][NP] f32 (204,800)
  float* ssq = (float*)(ws2 + 86016 + 204800);      // [B][NP] f32 (204,800)
  u16* pwb = (u16*)(ws2 + 86016 + 2 * 204800);      // [768][192] bf16
  u16* gwb = (u16*)(ws2 + 86016 + 2 * 204800 + 294912);  // [384][768] bf16
  u16* owb = (u16*)(ws2 + 86016 + 2 * 204800 + 294912 + 589824);  // [192][384] bf16

  k_prep<<<dim3(253), 256, 0, stream>>>(pw, gw, ow, pwb, gwb, owb, kfp);
  k_proj<<<dim3(49, 3, 16), 256, 0, stream>>>(x, pwb, pb, y0t);
  k_dwc<<<dim3(2688), 256, 0, stream>>>(y0t, cw, cb, yt, kfp);
  k_z<<<dim3(13, 16), 256, 0, stream>>>(yt, kfp, zinv, ssq);
  k_vk<<<dim3(336), 256, 0, stream>>>(yt, vkpart);
  k_vkred<<<dim3(576), 256, 0, stream>>>(vkpart, vkb);
  k_gateattn<<<dim3(800), 256, 0, stream>>>(yt, zinv, vkb, gwb, gb, attnt, ssq);
  k_out<<<dim3(49, 16), 256, 0, stream>>>(attnt, yt, owb, ob, anw, svw, ssq, out);
}

// Round 14
// 261.539 us; speedup vs baseline: 1.2376x; 1.2376x over previous
//
#include <hip/hip_runtime.h>
#include <hip/hip_bf16.h>

typedef unsigned short u16;
typedef __attribute__((ext_vector_type(8))) short bf16x8;
typedef __attribute__((ext_vector_type(4))) float f32x4;

constexpr int B_ = 16, C_ = 192, H_ = 56, W_ = 56;
constexpr int N_ = H_ * W_;   // 3136
constexpr int A_ = 768;       // attn_dim
constexpr int Dq = 192;       // d_qk
constexpr int Vd = 384;       // d_v
constexpr float EPSf = 1e-6f;

union U8 { bf16x8 v; u16 s[8]; unsigned u[4]; };

__device__ __forceinline__ float bits2f(u16 u) {
  return __uint_as_float(((unsigned)u) << 16);
}
__device__ __forceinline__ u16 f2bits(float f) {
  __hip_bfloat16 h = __float2bfloat16(f);
  u16 u;
  __builtin_memcpy(&u, &h, sizeof(u));
  return u;
}
__device__ __forceinline__ float silu_f(float v) { return v / (1.0f + __expf(-v)); }
__device__ __forceinline__ float sigm_f(float v) { return 1.0f / (1.0f + __expf(-v)); }

__device__ __forceinline__ f32x4 MFMA(bf16x8 a, bf16x8 b, f32x4 c) {
  return __builtin_amdgcn_mfma_f32_16x16x32_bf16(a, b, c, 0, 0, 0);
}
__device__ __forceinline__ int swz(int row) { return (row & 7) ^ ((row >> 3) & 7); }

// ============ K0: weight pre-convert f32 -> bf16; block 252 zeros kfp + ssq
__global__ __launch_bounds__(256) void k_prep(const float* __restrict__ pw,
                                              const float* __restrict__ gw,
                                              const float* __restrict__ ow,
                                              u16* __restrict__ pwb,
                                              u16* __restrict__ gwb,
                                              u16* __restrict__ owb,
                                              float* __restrict__ kfp,
                                              float* __restrict__ ssq) {
  const int bid = blockIdx.x;
  if (bid == 252) {
    const int tot = B_ * Dq + B_ * N_;
    for (int i = threadIdx.x; i < tot; i += 256) {
      if (i < B_ * Dq) kfp[i] = 0.f;
      else ssq[i - B_ * Dq] = 0.f;
    }
    return;
  }
  const size_t base = ((size_t)bid * 256 + threadIdx.x) * 8;
  const float* src;
  u16* dst;
  size_t off;
  if (bid < 72) { src = pw; dst = pwb; off = base; }
  else if (bid < 216) { src = gw; dst = gwb; off = base - 147456; }
  else { src = ow; dst = owb; off = base - 442368; }
  float4 v0 = *(const float4*)&src[off];
  float4 v1 = *(const float4*)&src[off + 4];
  U8 r;
  r.s[0] = f2bits(v0.x); r.s[1] = f2bits(v0.y); r.s[2] = f2bits(v0.z); r.s[3] = f2bits(v0.w);
  r.s[4] = f2bits(v1.x); r.s[5] = f2bits(v1.y); r.s[6] = f2bits(v1.z); r.s[7] = f2bits(v1.w);
  *(bf16x8*)&dst[off] = r.v;
}

// ============ K1: proj GEMM  y0t[b][n][o] = sum_c pw[o,c]*x[b,c,n] + pb[o]
__global__ __launch_bounds__(256) void k_proj(const float* __restrict__ x,
                                              const u16* __restrict__ pwb,
                                              const float* __restrict__ pb,
                                              u16* __restrict__ y0t) {
  const int n0 = blockIdx.x * 64;
  const int oy = blockIdx.y;  // 0..2
  const int b = blockIdx.z;
  __shared__ u16 Xt[64][200];  // [n][c], 400B stride
  __shared__ u16 Wa[256][32];  // [o][k32], swizzled 16B blocks
  const int t = threadIdx.x;
  const int lane = t & 63, wid = t >> 6;
  const int fr = lane & 15, fg = lane >> 4;

  // stage Xt: x[b][c][n] -> Xt[n][c]
  {
    const int p = t & 31, co = t >> 5;
    const float* xb = x + (size_t)b * C_ * N_ + n0 + 2 * p;
#pragma unroll
    for (int rnd = 0; rnd < 3; ++rnd) {
      const int c0 = rnd * 64 + co * 8;
      float2 v[8];
#pragma unroll
      for (int i = 0; i < 8; ++i) v[i] = *(const float2*)&xb[(size_t)(c0 + i) * N_];
      U8 r0, r1;
#pragma unroll
      for (int i = 0; i < 8; ++i) { r0.s[i] = f2bits(v[i].x); r1.s[i] = f2bits(v[i].y); }
      *(bf16x8*)&Xt[2 * p][c0] = r0.v;
      *(bf16x8*)&Xt[2 * p + 1][c0] = r1.v;
    }
  }

  f32x4 acc[4][4];
#pragma unroll
  for (int mi = 0; mi < 4; ++mi)
#pragma unroll
    for (int ni = 0; ni < 4; ++ni) acc[mi][ni] = (f32x4){0.f, 0.f, 0.f, 0.f};

  const int orow_c = t >> 2, oct_c = t & 3;
  U8 wreg[4];
#pragma unroll
  for (int jj = 0; jj < 4; ++jj)
    wreg[jj].v = *(const bf16x8*)&pwb[(size_t)(oy * 256 + orow_c + 64 * jj) * C_ + oct_c * 8];

  for (int ks = 0; ks < 6; ++ks) {
    __syncthreads();
#pragma unroll
    for (int jj = 0; jj < 4; ++jj) {
      const int orow = orow_c + 64 * jj;
      const int sw = (orow >> 1) & 3;
      *(bf16x8*)&Wa[orow][(oct_c ^ sw) * 8] = wreg[jj].v;
    }
    __syncthreads();
    if (ks < 5) {
#pragma unroll
      for (int jj = 0; jj < 4; ++jj)
        wreg[jj].v = *(const bf16x8*)&pwb[(size_t)(oy * 256 + orow_c + 64 * jj) * C_ +
                                          (ks + 1) * 32 + oct_c * 8];
    }
    bf16x8 bfrag[4];
#pragma unroll
    for (int ni = 0; ni < 4; ++ni)
      bfrag[ni] = *(const bf16x8*)&Xt[ni * 16 + fr][ks * 32 + fg * 8];
    __builtin_amdgcn_s_setprio(1);
#pragma unroll
    for (int mi = 0; mi < 4; ++mi) {
      const int ar = wid * 64 + mi * 16 + fr;
      bf16x8 a = *(const bf16x8*)&Wa[ar][(fg ^ ((ar >> 1) & 3)) * 8];
#pragma unroll
      for (int ni = 0; ni < 4; ++ni) acc[mi][ni] = MFMA(a, bfrag[ni], acc[mi][ni]);
    }
    __builtin_amdgcn_s_setprio(0);
  }
#pragma unroll
  for (int mi = 0; mi < 4; ++mi) {
    const int o4 = oy * 256 + wid * 64 + mi * 16 + fg * 4;
    const float b0 = pb[o4], b1 = pb[o4 + 1], b2 = pb[o4 + 2], b3 = pb[o4 + 3];
#pragma unroll
    for (int ni = 0; ni < 4; ++ni) {
      const int n = n0 + ni * 16 + fr;
      ushort4 pk;
      pk.x = f2bits(acc[mi][ni][0] + b0);
      pk.y = f2bits(acc[mi][ni][1] + b1);
      pk.z = f2bits(acc[mi][ni][2] + b2);
      pk.w = f2bits(acc[mi][ni][3] + b3);
      *(ushort4*)&y0t[((size_t)b * N_ + n) * A_ + o4] = pk;
    }
  }
}

// ============ K2: depthwise 3x3 + bias + residual, sliding-window; fused kfmean atomics
__global__ __launch_bounds__(256) void k_dwc(const u16* __restrict__ y0t,
                                             const float* __restrict__ cw,
                                             const float* __restrict__ cb,
                                             u16* __restrict__ yt,
                                             float* __restrict__ kfp) {
  const int pid = blockIdx.x;
  const int L = (pid & 7) * 336 + (pid >> 3);  // 2688 = 8*336
  const int h = L % 56, at = (L / 56) % 3, b = L / 168;
  const int t = threadIdx.x;
  const int a = at * 256 + (t & 31) * 8;
  const int ws0 = (t >> 5) * 7;  // 7-wide consecutive w strip
  float w9[9][8];
  float bias[8];
#pragma unroll
  for (int j = 0; j < 8; ++j) {
    bias[j] = cb[a + j];
#pragma unroll
    for (int k = 0; k < 9; ++k) w9[k][j] = cw[(a + j) * 9 + k];
  }
  const u16* src = y0t + (size_t)b * N_ * A_ + a;
  u16* dst = yt + (size_t)b * N_ * A_ + a;
  const bool hok0 = h > 0, hok2 = h < 55;

  U8 cm[3], cc[3], cp[3];  // cols w-1, w, w+1; rows h-1,h,h+1
  auto zero8 = [](U8& x) { x.u[0] = x.u[1] = x.u[2] = x.u[3] = 0u; };
  auto loadcol = [&](U8 col[3], int w) {
    if ((unsigned)w < 56u) {
      if (hok0) col[0].v = *(const bf16x8*)&src[(size_t)((h - 1) * 56 + w) * A_];
      else zero8(col[0]);
      col[1].v = *(const bf16x8*)&src[(size_t)(h * 56 + w) * A_];
      if (hok2) col[2].v = *(const bf16x8*)&src[(size_t)((h + 1) * 56 + w) * A_];
      else zero8(col[2]);
    } else {
      zero8(col[0]); zero8(col[1]); zero8(col[2]);
    }
  };
  loadcol(cm, ws0 - 1);
  loadcol(cc, ws0);

  float kacc[8] = {0.f, 0.f, 0.f, 0.f, 0.f, 0.f, 0.f, 0.f};
#pragma unroll
  for (int i = 0; i < 7; ++i) {
    const int w = ws0 + i;
    loadcol(cp, w + 1);
    U8 o;
#pragma unroll
    for (int j = 0; j < 8; ++j) {
      float s = bias[j] + bits2f(cc[1].s[j]);  // bias + residual(center)
      s = fmaf(w9[0][j], bits2f(cm[0].s[j]), s);
      s = fmaf(w9[1][j], bits2f(cc[0].s[j]), s);
      s = fmaf(w9[2][j], bits2f(cp[0].s[j]), s);
      s = fmaf(w9[3][j], bits2f(cm[1].s[j]), s);
      s = fmaf(w9[4][j], bits2f(cc[1].s[j]), s);
      s = fmaf(w9[5][j], bits2f(cp[1].s[j]), s);
      s = fmaf(w9[6][j], bits2f(cm[2].s[j]), s);
      s = fmaf(w9[7][j], bits2f(cc[2].s[j]), s);
      s = fmaf(w9[8][j], bits2f(cp[2].s[j]), s);
      o.s[j] = f2bits(s);
      const int ch = a + j;
      if (ch >= 192 && ch < 384) kacc[j] += silu_f(s);
    }
    *(bf16x8*)&dst[(size_t)(h * 56 + w) * A_] = o.v;
#pragma unroll
    for (int r = 0; r < 3; ++r) { cm[r] = cc[r]; cc[r] = cp[r]; }
  }

  // block-reduce kacc over the 8 w-strips, one atomicAdd per channel in [192,384)
  __shared__ float red[8][256];
  if (at < 2) {
    const int cbase = (t & 31) * 8, wl = t >> 5;
#pragma unroll
    for (int j = 0; j < 8; ++j) red[wl][cbase + j] = kacc[j];
    __syncthreads();
    float s = 0.f;
#pragma unroll
    for (int i = 0; i < 8; ++i) s += red[i][t];
    const int ac = at * 256 + t;
    if (ac >= 192 && ac < 384) atomicAdd(&kfp[b * Dq + (ac - 192)], s);
  }
}

// ============ K5: vk GEMM, split-K over N (7 chunks), 128v x 192d tiles.
__global__ __launch_bounds__(256) void k_vk(const u16* __restrict__ yt,
                                            float* __restrict__ vkpart) {
  const int pid = blockIdx.x;  // 336 = 8*42
  const int L = (pid & 7) * 42 + (pid >> 3);
  const int ns = L % 7;
  const int vblk = (L / 7) % 3;
  const int b = L / 21;
  const int t = threadIdx.x;
  const int lane = t & 63, wid = t >> 6;
  const int fr = lane & 15, fg = lane >> 4;
  const int vbase = (wid >> 1) * 64, dbase = (wid & 1) * 96;

  __shared__ u16 T[320 * 64];  // rows 0..191: K(d, silu); rows 192..319: V
  unsigned* T32 = (unsigned*)T;

  const int oct0 = t & 7;
  const int pair = (t >> 3) & 31;
  const int nb0 = ns * 448;

  U8 pre[5][2];
  auto load_pre = [&](int n0) {
    const int n = nb0 + n0 + pair * 2;
#pragma unroll
    for (int j = 0; j < 5; ++j) {
      const int oct = oct0 + 8 * j;
      const u16* srcp;
      if (j < 3)
        srcp = yt + ((size_t)b * N_ + n) * A_ + 192 + oct * 8;
      else
        srcp = yt + ((size_t)b * N_ + n) * A_ + 384 + vblk * 128 + (oct - 24) * 8;
      pre[j][0].v = *(const bf16x8*)srcp;
      pre[j][1].v = *(const bf16x8*)(srcp + A_);
      if (j < 3) {
#pragma unroll
        for (int i = 0; i < 8; ++i) {
          pre[j][0].s[i] = f2bits(silu_f(bits2f(pre[j][0].s[i])));
          pre[j][1].s[i] = f2bits(silu_f(bits2f(pre[j][1].s[i])));
        }
      }
    }
  };

  f32x4 acc[4][6];
#pragma unroll
  for (int mi = 0; mi < 4; ++mi)
#pragma unroll
    for (int ni = 0; ni < 6; ++ni) acc[mi][ni] = (f32x4){0.f, 0.f, 0.f, 0.f};

  load_pre(0);
  for (int s = 0; s < 7; ++s) {
    __syncthreads();
#pragma unroll
    for (int j = 0; j < 5; ++j) {
      const int rowb = (oct0 + 8 * j) * 8;
#pragma unroll
      for (int i = 0; i < 8; ++i) {
        const int row = rowb + i;
        const int sw = swz(row);
        const unsigned val =
            ((unsigned)pre[j][0].s[i] & 0xffffu) | (((unsigned)pre[j][1].s[i]) << 16);
        T32[row * 32 + (pair ^ (sw << 2))] = val;
      }
    }
    __syncthreads();
    if (s < 6) load_pre((s + 1) * 64);
    __builtin_amdgcn_s_setprio(1);
#pragma unroll
    for (int kf2 = 0; kf2 < 2; ++kf2) {
      bf16x8 bfrag[6];
#pragma unroll
      for (int ni = 0; ni < 6; ++ni) {
        const int row = dbase + ni * 16 + fr;
        bfrag[ni] = *(const bf16x8*)&T[row * 64 + ((kf2 * 32 + fg * 8) ^ (swz(row) << 3))];
      }
#pragma unroll
      for (int mi = 0; mi < 4; ++mi) {
        const int row = 192 + vbase + mi * 16 + fr;
        bf16x8 a = *(const bf16x8*)&T[row * 64 + ((kf2 * 32 + fg * 8) ^ (swz(row) << 3))];
#pragma unroll
        for (int ni = 0; ni < 6; ++ni) acc[mi][ni] = MFMA(a, bfrag[ni], acc[mi][ni]);
      }
    }
    __builtin_amdgcn_s_setprio(0);
  }
  float* base = vkpart + (((size_t)ns * 16 + b) * 3 + vblk) * (128 * 192);
#pragma unroll
  for (int mi = 0; mi < 4; ++mi)
#pragma unroll
    for (int ni = 0; ni < 6; ++ni) {
      const int v = vbase + mi * 16 + fg * 4;
      const int d = dbase + ni * 16 + fr;
      float* o = base + (size_t)v * 192 + d;
      o[0] = acc[mi][ni][0];
      o[192] = acc[mi][ni][1];
      o[384] = acc[mi][ni][2];
      o[576] = acc[mi][ni][3];
    }
}

// ============ K5b: reduce 7 partials -> vkb bf16 [b][384][192] (with 1/N)
__global__ __launch_bounds__(256) void k_vkred(const float* __restrict__ vkpart,
                                               u16* __restrict__ vkb) {
  const size_t e = ((size_t)blockIdx.x * 256 + threadIdx.x) * 8;
  constexpr size_t NSSTRIDE = (size_t)16 * 3 * 128 * 192;
  float4 s0 = {0, 0, 0, 0}, s1 = {0, 0, 0, 0};
#pragma unroll
  for (int ns = 0; ns < 7; ++ns) {
    float4 a0 = *(const float4*)&vkpart[ns * NSSTRIDE + e];
    float4 a1 = *(const float4*)&vkpart[ns * NSSTRIDE + e + 4];
    s0.x += a0.x; s0.y += a0.y; s0.z += a0.z; s0.w += a0.w;
    s1.x += a1.x; s1.y += a1.y; s1.z += a1.z; s1.w += a1.w;
  }
  const float sc = 1.0f / (float)N_;
  U8 r;
  r.s[0] = f2bits(s0.x * sc); r.s[1] = f2bits(s0.y * sc);
  r.s[2] = f2bits(s0.z * sc); r.s[3] = f2bits(s0.w * sc);
  r.s[4] = f2bits(s1.x * sc); r.s[5] = f2bits(s1.y * sc);
  r.s[6] = f2bits(s1.z * sc); r.s[7] = f2bits(s1.w * sc);
  *(bf16x8*)&vkb[e] = r.v;
}

// ============ K6: fused attn0 + gate + in-kernel z + ssq epilogue.
// Double-buffered LDS, one barrier/iter, KSTEP=64, 15 iters (3 attn0 + 12 gate).
__global__ __launch_bounds__(256) void k_gateattn(const u16* __restrict__ yt,
                                                  const float* __restrict__ kfp,
                                                  const u16* __restrict__ vkb,
                                                  const u16* __restrict__ gwb,
                                                  const float* __restrict__ gb,
                                                  u16* __restrict__ attnt,
                                                  float* __restrict__ ssq) {
  const int pid = blockIdx.x;
  const int L = (pid & 7) * 196 + (pid >> 3);  // 1568 = 8*196
  const int vh = L & 1;
  const int n0 = ((L >> 1) % 49) * 64;
  const int b = L / 98;
  const int t = threadIdx.x;
  const int lane = t & 63, wid = t >> 6, wm = wid >> 1, wn = wid & 1;
  const int fr = lane & 15, fg = lane >> 4;
  __shared__ u16 T[2][256 * 64];  // dbuf; rows 0..191: W, 192..255: X (swizzled octets)
  __shared__ float zl[64];
  __shared__ float kfs[192];
  if (t < 192) kfs[t] = kfp[b * Dq + t] * (1.0f / (float)N_);
  const u16* yb = yt + ((size_t)b * N_ + n0) * A_;
  const u16* wb0 = vkb + ((size_t)b * Vd + vh * 192) * 192;  // attn0 W, stride 192
  const u16* wb1 = gwb + (size_t)(vh * 192) * A_;            // gate W, stride 768

  const int oct = t & 7, rowb = t >> 3;  // 8 octets, 32 row-groups
  U8 pre[8];
  float zp[2] = {0.f, 0.f};  // z partials for n-rows rowb, rowb+32
  auto loadPre = [&](int nit) {
    if (nit < 3) {
      const int ks = nit * 64;
#pragma unroll
      for (int j = 0; j < 6; ++j)
        pre[j].v = *(const bf16x8*)&wb0[(size_t)(rowb + 32 * j) * 192 + ks + oct * 8];
#pragma unroll
      for (int j = 6; j < 8; ++j)
        pre[j].v = *(const bf16x8*)&yb[(size_t)(rowb + 32 * (j - 6)) * A_ + ks + oct * 8];
    } else {
      const int ks = (nit - 3) * 64;
#pragma unroll
      for (int j = 0; j < 6; ++j)
        pre[j].v = *(const bf16x8*)&wb1[(size_t)(rowb + 32 * j) * A_ + ks + oct * 8];
#pragma unroll
      for (int j = 6; j < 8; ++j)
        pre[j].v = *(const bf16x8*)&yb[(size_t)(rowb + 32 * (j - 6)) * A_ + ks + oct * 8];
    }
  };
  auto writeStage = [&](int nit, int buf) {
    const bool sl = (nit < 3);
    const int kbase = nit * 64 + oct * 8;
    u16* Tb = &T[buf][0];
#pragma unroll
    for (int j = 0; j < 8; ++j) {
      const int r = rowb + 32 * j;
      U8 w = pre[j];
      if (sl && j >= 6) {
#pragma unroll
        for (int i = 0; i < 8; ++i) {
          const float sv = silu_f(bits2f(w.s[i]));
          zp[j - 6] = fmaf(kfs[kbase + i], sv, zp[j - 6]);
          w.s[i] = f2bits(sv);
        }
      }
      *(bf16x8*)&Tb[r * 64 + ((oct * 8) ^ (swz(r) << 3))] = w.v;
    }
  };

  f32x4 acc[6][2];
#pragma unroll
  for (int mi = 0; mi < 6; ++mi)
#pragma unroll
    for (int ni = 0; ni < 2; ++ni) acc[mi][ni] = (f32x4){0.f, 0.f, 0.f, 0.f};
  uint2 pp[6][2];

  // prologue: kfs visible, fill buf0 for iter 0, iter-1 loads in regs
  loadPre(0);
  __syncthreads();  // kfs ready before writeStage's z-accumulation
  writeStage(0, 0);
  loadPre(1);
  __syncthreads();

  for (int it = 0; it < 15; ++it) {
    const int cur = it & 1;
    if (it < 14) writeStage(it + 1, cur ^ 1);  // fill other buffer (consumes pre)
    if (it == 1) {  // z partials complete (ks 0,64,128 staged): reduce over octets
      float z0 = zp[0], z1 = zp[1];
      z0 += __shfl_xor(z0, 1); z0 += __shfl_xor(z0, 2); z0 += __shfl_xor(z0, 4);
      z1 += __shfl_xor(z1, 1); z1 += __shfl_xor(z1, 2); z1 += __shfl_xor(z1, 4);
      if (oct == 0) {
        zl[rowb] = 1.0f / (z0 + EPSf);
        zl[rowb + 32] = 1.0f / (z1 + EPSf);
      }
    }
    if (it < 13) loadPre(it + 2);  // issue next global loads
    const u16* Tb = &T[cur][0];
    __builtin_amdgcn_s_setprio(1);
#pragma unroll
    for (int kf2 = 0; kf2 < 2; ++kf2) {
      bf16x8 bfr[2];
#pragma unroll
      for (int ni = 0; ni < 2; ++ni) {
        const int row = 192 + wn * 32 + ni * 16 + fr;
        bfr[ni] = *(const bf16x8*)&Tb[row * 64 + ((kf2 * 32 + fg * 8) ^ (swz(row) << 3))];
      }
#pragma unroll
      for (int mi = 0; mi < 6; ++mi) {
        const int row = wm * 96 + mi * 16 + fr;
        bf16x8 a = *(const bf16x8*)&Tb[row * 64 + ((kf2 * 32 + fg * 8) ^ (swz(row) << 3))];
        acc[mi][0] = MFMA(a, bfr[0], acc[mi][0]);
        acc[mi][1] = MFMA(a, bfr[1], acc[mi][1]);
      }
    }
    __builtin_amdgcn_s_setprio(0);
    if (it == 2) {  // attn0 done: apply 1/z (zl ready: written it==1, barrier between)
#pragma unroll
      for (int mi = 0; mi < 6; ++mi)
#pragma unroll
        for (int ni = 0; ni < 2; ++ni) {
          const float z = zl[wn * 32 + ni * 16 + fr];
          unsigned a0 = ((unsigned)f2bits(acc[mi][ni][0] * z) & 0xffffu) |
                        (((unsigned)f2bits(acc[mi][ni][1] * z) & 0xffffu) << 16);
          unsigned a1 = ((unsigned)f2bits(acc[mi][ni][2] * z) & 0xffffu) |
                        (((unsigned)f2bits(acc[mi][ni][3] * z) & 0xffffu) << 16);
          pp[mi][ni] = make_uint2(a0, a1);
          acc[mi][ni] = (f32x4){0.f, 0.f, 0.f, 0.f};
        }
    }
    __syncthreads();  // one barrier per iter: cur consumed, cur^1 published
  }

  // ---- combine, write attnt[n][v], accumulate ssq
  float ssqa[2] = {0.f, 0.f};
#pragma unroll
  for (int mi = 0; mi < 6; ++mi) {
    const int vb = vh * 192 + wm * 96 + mi * 16 + fg * 4;
    const float g0 = gb[vb], g1 = gb[vb + 1], g2 = gb[vb + 2], g3 = gb[vb + 3];
#pragma unroll
    for (int ni = 0; ni < 2; ++ni) {
      const int n = n0 + wn * 32 + ni * 16 + fr;
      const uint2 p = pp[mi][ni];
      const float pv0 = bits2f((u16)(p.x & 0xffffu)), pv1 = bits2f((u16)(p.x >> 16));
      const float pv2 = bits2f((u16)(p.y & 0xffffu)), pv3 = bits2f((u16)(p.y >> 16));
      const float q0 = pv0 * sigm_f(acc[mi][ni][0] + g0);
      const float q1 = pv1 * sigm_f(acc[mi][ni][1] + g1);
      const float q2 = pv2 * sigm_f(acc[mi][ni][2] + g2);
      const float q3 = pv3 * sigm_f(acc[mi][ni][3] + g3);
      ushort4 o;
      o.x = f2bits(q0);
      o.y = f2bits(q1);
      o.z = f2bits(q2);
      o.w = f2bits(q3);
      *(ushort4*)&attnt[((size_t)b * N_ + n) * Vd + vb] = o;
      ssqa[ni] += q0 * q0 + q1 * q1 + q2 * q2 + q3 * q3;
    }
  }
#pragma unroll
  for (int ni = 0; ni < 2; ++ni) {
    float ss = ssqa[ni];
    ss += __shfl_xor(ss, 16);
    ss += __shfl_xor(ss, 32);
    if (fg == 0) {
      const int n = n0 + wn * 32 + ni * 16 + fr;
      atomicAdd(&ssq[(size_t)b * N_ + n], ss);
    }
  }
}

// ============ K7: final combine + out GEMM; rinv from precomputed ssq.
__global__ __launch_bounds__(256) void k_out(const u16* __restrict__ attnt,
                                             const u16* __restrict__ yt,
                                             const u16* __restrict__ owb,
                                             const float* __restrict__ ob,
                                             const float* __restrict__ anw,
                                             const float* __restrict__ svw,
                                             const float* __restrict__ ssq,
                                             float* __restrict__ out) {
  const int n0 = blockIdx.x * 64;
  const int b = blockIdx.y;
  __shared__ u16 T[256 * 64];  // rows 0..191: W(ow); rows 192..255: X (transformed)
  __shared__ float anws[384], svws[384];
  __shared__ float rinv[64];
  const int t = threadIdx.x;
  const int lane = t & 63, wid = t >> 6, wm = wid >> 1, wn = wid & 1;
  const int fr = lane & 15, fg = lane >> 4;
  for (int i = t; i < 384; i += 256) {
    anws[i] = anw[i];
    svws[i] = svw[i];
  }
  if (t < 64)
    rinv[t] = rsqrtf(ssq[(size_t)b * N_ + n0 + t] * (1.0f / (float)Vd) + EPSf);

  const int oct = t & 7, rowb = t >> 3;
  U8 preW[6], preA[2], preV[2];
  auto loadPre = [&](int it) {
    const int ks = it * 64;
#pragma unroll
    for (int j = 0; j < 6; ++j)
      preW[j].v = *(const bf16x8*)&owb[(size_t)(rowb + 32 * j) * Vd + ks + oct * 8];
#pragma unroll
    for (int j = 0; j < 2; ++j) {
      const int n = rowb + 32 * j;
      preA[j].v = *(const bf16x8*)&attnt[((size_t)b * N_ + n0 + n) * Vd + ks + oct * 8];
      preV[j].v = *(const bf16x8*)&yt[((size_t)b * N_ + n0 + n) * A_ + 384 + ks + oct * 8];
    }
  };

  f32x4 acc[6][2];
#pragma unroll
  for (int mi = 0; mi < 6; ++mi)
#pragma unroll
    for (int ni = 0; ni < 2; ++ni) acc[mi][ni] = (f32x4){0.f, 0.f, 0.f, 0.f};

  loadPre(0);
  __syncthreads();  // rinv/anws ready
  for (int it = 0; it < 6; ++it) {
#pragma unroll
    for (int j = 0; j < 6; ++j) {
      const int r = rowb + 32 * j;
      *(bf16x8*)&T[r * 64 + ((oct * 8) ^ (swz(r) << 3))] = preW[j].v;
    }
#pragma unroll
    for (int j = 0; j < 2; ++j) {
      const int n = rowb + 32 * j;
      const int r = 192 + n;
      const float ri = rinv[n];
      const int col0 = it * 64 + oct * 8;
      U8 o;
#pragma unroll
      for (int k = 0; k < 8; ++k)
        o.s[k] = f2bits(bits2f(preA[j].s[k]) * ri * anws[col0 + k] +
                        bits2f(preV[j].s[k]) * svws[col0 + k]);
      *(bf16x8*)&T[r * 64 + ((oct * 8) ^ (swz(r) << 3))] = o.v;
    }
    __syncthreads();
    if (it < 5) loadPre(it + 1);
    __builtin_amdgcn_s_setprio(1);
#pragma unroll
    for (int kf2 = 0; kf2 < 2; ++kf2) {
      bf16x8 bfr[2];
#pragma unroll
      for (int ni = 0; ni < 2; ++ni) {
        const int row = 192 + wn * 32 + ni * 16 + fr;
        bfr[ni] = *(const bf16x8*)&T[row * 64 + ((kf2 * 32 + fg * 8) ^ (swz(row) << 3))];
      }
#pragma unroll
      for (int mi = 0; mi < 6; ++mi) {
        const int row = wm * 96 + mi * 16 + fr;
        bf16x8 a = *(const bf16x8*)&T[row * 64 + ((kf2 * 32 + fg * 8) ^ (swz(row) << 3))];
        acc[mi][0] = MFMA(a, bfr[0], acc[mi][0]);
        acc[mi][1] = MFMA(a, bfr[1], acc[mi][1]);
      }
    }
    __builtin_amdgcn_s_setprio(0);
    if (it < 5) __syncthreads();  // T consumed; next stage may overwrite
  }
#pragma unroll
  for (int mi = 0; mi < 6; ++mi) {
    const int c = wm * 96 + mi * 16 + fg * 4;
    const float b0 = ob[c], b1 = ob[c + 1], b2 = ob[c + 2], b3 = ob[c + 3];
#pragma unroll
    for (int ni = 0; ni < 2; ++ni) {
      const int n = n0 + wn * 32 + ni * 16 + fr;
      float* o = out + ((size_t)b * C_ + c) * N_ + n;
      o[0 * N_] = acc[mi][ni][0] + b0;
      o[1 * N_] = acc[mi][ni][1] + b1;
      o[2 * N_] = acc[mi][ni][2] + b2;
      o[3 * N_] = acc[mi][ni][3] + b3;
    }
  }
}

extern "C" void kernel_launch(void* const* d_in, const int* in_sizes, int n_in,
                              void* d_out, int out_size, void* d_ws, size_t ws_size,
                              hipStream_t stream) {
  (void)in_sizes; (void)n_in; (void)out_size; (void)ws_size;
  const float* x = (const float*)d_in[0];
  const float* pw = (const float*)d_in[1];
  const float* pb = (const float*)d_in[2];
  const float* cw = (const float*)d_in[3];
  const float* cb = (const float*)d_in[4];
  const float* gw = (const float*)d_in[5];
  const float* gb = (const float*)d_in[6];
  const float* anw = (const float*)d_in[7];
  const float* svw = (const float*)d_in[8];
  const float* ow = (const float*)d_in[9];
  const float* ob = (const float*)d_in[10];
  float* out = (float*)d_out;

  char* ws = (char*)d_ws;
  const size_t szY = (size_t)B_ * N_ * A_ * 2;  // 77,070,336
  u16* y0t = (u16*)(ws);
  u16* attnt = (u16*)(ws);                          // [B][N][384] bf16 (38,535,168)
  float* vkpart = (float*)(ws + 38535168);          // [7][16][3][128][192] f32 (33,030,144)
  u16* vkb = (u16*)(ws + 71565312);                 // [16][384][192] bf16 (2,359,296)
  u16* yt = (u16*)(ws + szY);                       // [B][N][A] bf16
  char* ws2 = ws + 2 * szY;
  float* kfp = (float*)(ws2);                       // [16][192] f32 (12,288)
  float* ssq = (float*)(ws2 + 86016);               // [B][N] f32 (200,704)
  u16* pwb = (u16*)(ws2 + 86016 + 200704);          // [768][192] bf16
  u16* gwb = (u16*)(ws2 + 86016 + 200704 + 294912); // [384][768] bf16
  u16* owb = (u16*)(ws2 + 86016 + 200704 + 294912 + 589824);  // [192][384] bf16

  k_prep<<<dim3(253), 256, 0, stream>>>(pw, gw, ow, pwb, gwb, owb, kfp, ssq);
  k_proj<<<dim3(49, 3, 16), 256, 0, stream>>>(x, pwb, pb, y0t);
  k_dwc<<<dim3(2688), 256, 0, stream>>>(y0t, cw, cb, yt, kfp);
  k_vk<<<dim3(336), 256, 0, stream>>>(yt, vkpart);
  k_vkred<<<dim3(576), 256, 0, stream>>>(vkpart, vkb);
  k_gateattn<<<dim3(1568), 256, 0, stream>>>(yt, kfp, vkb, gwb, gb, attnt, ssq);
  k_out<<<dim3(49, 16), 256, 0, stream>>>(attnt, yt, owb, ob, anw, svw, ssq, out);
}